// Round 2
// baseline (328.504 us; speedup 1.0000x reference)
//
#include <hip/hip_runtime.h>

// Problem constants (fixed by reference setup_inputs):
//   d: (B=64, T=12, C=64, S2=1024) fp32, m: same shape int32,
//   poi_index: (S2,) int, side=32 (S2 = side*side = 1024).
#define B_  64
#define T_  12
#define C_  64
#define S2_ 1024

// Kernel 1: partial[b*2+ch][s] = OR over 32 c's of m[b, T-1, ch*32+c, s].
// Plain int4 stores -> no memset, no atomics. Grid 128 blocks x 256 threads.
// Each wave load: 64 lanes x 16 B = 1 KB, fully coalesced. ILP = 32 per thread.
__global__ void mask_partial(const int* __restrict__ m, int* __restrict__ partial) {
    const int ch = blockIdx.x & 1;        // c-half: 0 or 1
    const int b  = blockIdx.x >> 1;       // 0..63
    const int s4 = threadIdx.x * 4;
    const int* base = m + ((size_t)(b * T_ + (T_ - 1)) * C_ + ch * 32) * S2_;
    int4 acc = make_int4(0, 0, 0, 0);
#pragma unroll
    for (int c = 0; c < 32; ++c) {
        const int4 v = *(const int4*)(base + (size_t)c * S2_ + s4);
        acc.x |= v.x; acc.y |= v.y; acc.z |= v.z; acc.w |= v.w;
    }
    *(int4*)(partial + (size_t)blockIdx.x * S2_ + s4) = acc;
}

// Kernel 2: phase A — flags[s] = OR over the 128 partial rows (L2-resident),
// staged in LDS. phase B — out[b,c,s] = d[b,T-1,c,s] + (flags[s]==0 ?
// d[b,T-1,c,poi[s]] : 0), 16 (b,c) rows per block, int4 everywhere.
__global__ void auxcmp(const float* __restrict__ d,
                       const int* __restrict__ partial,
                       const int* __restrict__ poi,
                       float* __restrict__ out) {
    __shared__ int sflags[S2_];
    const int t  = threadIdx.x;
    const int s4 = t * 4;

    // Phase A: OR-reduce 128 partial rows for this thread's 4 s-values.
    int4 f = make_int4(0, 0, 0, 0);
#pragma unroll 8
    for (int p = 0; p < 128; ++p) {
        const int4 v = *(const int4*)(partial + (size_t)p * S2_ + s4);
        f.x |= v.x; f.y |= v.y; f.z |= v.z; f.w |= v.w;
    }
    *(int4*)(sflags + s4) = f;
    __syncthreads();

    // Hoist per-s state into registers (same 4 s-values for all 16 rows).
    const int4 fl = *(const int4*)(sflags + s4);
    const int4 p4 = *(const int4*)(poi + s4);

    // Phase B: 16 consecutive (b,c) rows per block.
    const int row0 = blockIdx.x * 16;
#pragma unroll
    for (int i = 0; i < 16; ++i) {
        const int row = row0 + i;          // row = b*64 + c, in [0, 4096)
        const int b = row >> 6;
        const int c = row & 63;
        const size_t dbase = ((size_t)(b * T_ + (T_ - 1)) * C_ + c) * S2_;

        const float4 v = *(const float4*)(d + dbase + s4);
        float4 o = v;
        if (fl.x == 0) o.x += d[dbase + p4.x];
        if (fl.y == 0) o.y += d[dbase + p4.y];
        if (fl.z == 0) o.z += d[dbase + p4.z];
        if (fl.w == 0) o.w += d[dbase + p4.w];

        *(float4*)(out + (size_t)row * S2_ + s4) = o;
    }
}

extern "C" void kernel_launch(void* const* d_in, const int* in_sizes, int n_in,
                              void* d_out, int out_size, void* d_ws, size_t ws_size,
                              hipStream_t stream) {
    const float* d   = (const float*)d_in[0];
    const int*   m   = (const int*)d_in[1];
    const int*   poi = (const int*)d_in[2];
    float*       out = (float*)d_out;
    int*         partial = (int*)d_ws;   // 128 * 1024 ints = 512 KB, fully
                                         // overwritten every call (no init needed).

    mask_partial<<<dim3(128), dim3(256), 0, stream>>>(m, partial);
    auxcmp<<<dim3(256), dim3(256), 0, stream>>>(d, partial, poi, out);
}